// Round 5
// baseline (753.380 us; speedup 1.0000x reference)
//
#include <hip/hip_runtime.h>
#include <cstdint>

typedef __bf16 bf16;
typedef __bf16 bf16x4 __attribute__((ext_vector_type(4)));
typedef __bf16 bf16x8 __attribute__((ext_vector_type(8)));
typedef float floatx4 __attribute__((ext_vector_type(4)));
typedef float f32x16 __attribute__((ext_vector_type(16)));
typedef unsigned int uint2v __attribute__((ext_vector_type(2)));
typedef unsigned int uint4v __attribute__((ext_vector_type(4)));

typedef const __attribute__((address_space(1))) void* as1_cvptr;
typedef __attribute__((address_space(3))) void* as3_vptr;

__device__ __forceinline__ void gl_lds16(const void* g, void* l) {
  __builtin_amdgcn_global_load_lds((as1_cvptr)(uintptr_t)g,
                                   (as3_vptr)(uint32_t)(uintptr_t)l, 16, 0, 0);
}

#define EMBED 1024
#define SEQ 2048
#define NH 16
#define DH 64
// softmax scale folded into Q at projection time: 0.125 * log2(e)
#define QSCALE 0.18033688f

// pack two f32 -> one u32 of 2 bf16 (compiler fuses to v_cvt_pk_bf16_f32)
__device__ __forceinline__ unsigned pk_bf16(float a, float b) {
  unsigned short ua = __builtin_bit_cast(unsigned short, (bf16)a);
  unsigned short ub = __builtin_bit_cast(unsigned short, (bf16)b);
  return (unsigned)ua | ((unsigned)ub << 16);
}

// ---------------------------------------------------------------------------
// Kernel A: prep — grid (256,4). z<3: transpose+downcast W z; z=3: x->bf16.
// ---------------------------------------------------------------------------
__global__ __launch_bounds__(256) void prep(
    const float* __restrict__ x, const float* __restrict__ Wq,
    const float* __restrict__ Wk, const float* __restrict__ Wv,
    bf16* __restrict__ xb, bf16* __restrict__ Wqt,
    bf16* __restrict__ Wkt, bf16* __restrict__ Wvt) {
  __shared__ __align__(16) bf16 tile[64][72];
  int z = blockIdx.y;
  int t = threadIdx.x;
  if (z == 3) {
    size_t base = ((size_t)blockIdx.x * 256 + t) * 8;
#pragma unroll
    for (int it = 0; it < 8; ++it) {
      size_t i = base + (size_t)it * (256 * 256 * 8);
      floatx4 a = *(const floatx4*)(x + i);
      floatx4 bv = *(const floatx4*)(x + i + 4);
      bf16x8 o;
#pragma unroll
      for (int j = 0; j < 4; ++j) { o[j] = (bf16)a[j]; o[4 + j] = (bf16)bv[j]; }
      *(bf16x8*)(xb + i) = o;
    }
    return;
  }
  const float* W = (z == 0) ? Wq : (z == 1) ? Wk : Wv;
  bf16* Wt = (z == 0) ? Wqt : (z == 1) ? Wkt : Wvt;
  int k0 = (blockIdx.x >> 4) * 64, n0 = (blockIdx.x & 15) * 64;
  int r = t >> 3, c = (t & 7) * 8;
#pragma unroll
  for (int half = 0; half < 2; ++half) {
    const float* src = &W[(size_t)(k0 + r + half * 32) * EMBED + n0 + c];
    floatx4 f0 = *(const floatx4*)src;
    floatx4 f1 = *(const floatx4*)(src + 4);
    bf16x8 o;
#pragma unroll
    for (int j = 0; j < 4; ++j) { o[j] = (bf16)f0[j]; o[4 + j] = (bf16)f1[j]; }
    *(bf16x8*)&tile[r + half * 32][c] = o;
  }
  __syncthreads();
#pragma unroll
  for (int p = 0; p < 2; ++p) {
    int nn = (t >> 3) + p * 32, kk = (t & 7) * 8;
    bf16x8 v;
#pragma unroll
    for (int i = 0; i < 8; ++i) v[i] = tile[kk + i][nn];
    *(bf16x8*)&Wt[(size_t)(n0 + nn) * EMBED + k0 + kk] = v;
  }
}

// ---------------------------------------------------------------------------
// Kernel B v2: fused QKV projection. Operand order chosen per z so C rows =
// output's fastest dim -> packed bf16x4 (8B) stores.
// ---------------------------------------------------------------------------
__global__ __launch_bounds__(256) void qkv3(
    const bf16* __restrict__ Xb, const bf16* __restrict__ Wqt,
    const bf16* __restrict__ Wkt, const bf16* __restrict__ Wvt,
    bf16* __restrict__ qo, bf16* __restrict__ ko, bf16* __restrict__ vto) {
  __shared__ __align__(16) bf16 As[128 * 32];
  __shared__ __align__(16) bf16 Bs[128 * 32];

  int gid = blockIdx.x;
  int z = gid % 3;
  int rem = gid / 3;
  int bxx = rem & 7, byy = rem >> 3;  // bxx: outdim tile (8), byy: seq tile (32)

  const bf16* Wt = (z == 0) ? Wqt : (z == 1) ? Wkt : Wvt;
  bf16* out = (z == 0) ? qo : (z == 1) ? ko : vto;
  int m0 = (z == 2 ? byy : bxx) * 128;
  int n0 = (z == 2 ? bxx : byy) * 128;
  const bf16* Asrc = (z == 2) ? Xb : Wt;
  const bf16* Bsrc = (z == 2) ? Wt : Xb;
  float oscale = (z == 0) ? QSCALE : 1.0f;

  int t = threadIdx.x;
  int w = t >> 6, lane = t & 63, ln = lane & 15, quad = lane >> 4;
  int wm = (w >> 1) * 64, wn = (w & 1) * 64;

  floatx4 acc[4][4];
#pragma unroll
  for (int i = 0; i < 4; ++i)
#pragma unroll
    for (int j = 0; j < 4; ++j) acc[i][j] = floatx4{0.f, 0.f, 0.f, 0.f};

  int sr = t >> 2, sc = (t & 3) * 8;
  const bf16* ag = Asrc + (size_t)(m0 + sr) * EMBED + sc;
  const bf16* bg = Bsrc + (size_t)(n0 + sr) * EMBED + sc;
  bf16* al = As + sr * 32 + sc;
  bf16* bl = Bs + sr * 32 + sc;

  for (int k0 = 0; k0 < EMBED; k0 += 32) {
    __syncthreads();
    gl_lds16(ag + k0, al);
    gl_lds16(ag + k0 + (size_t)64 * EMBED, al + 64 * 32);
    gl_lds16(bg + k0, bl);
    gl_lds16(bg + k0 + (size_t)64 * EMBED, bl + 64 * 32);
    __syncthreads();

    bf16x8 afr[4], bfr[4];
#pragma unroll
    for (int i = 0; i < 4; ++i)
      afr[i] = *(const bf16x8*)&As[(wm + i * 16 + ln) * 32 + quad * 8];
#pragma unroll
    for (int j = 0; j < 4; ++j)
      bfr[j] = *(const bf16x8*)&Bs[(wn + j * 16 + ln) * 32 + quad * 8];
#pragma unroll
    for (int i = 0; i < 4; ++i)
#pragma unroll
      for (int j = 0; j < 4; ++j)
        acc[i][j] =
            __builtin_amdgcn_mfma_f32_16x16x32_bf16(afr[i], bfr[j], acc[i][j], 0, 0, 0);
  }

  // Epilogue: C/D 16x16 layout col=lane&15, row=quad*4+r (rows consecutive)
  if (z != 2) {
#pragma unroll
    for (int i = 0; i < 4; ++i) {
      int od = m0 + wm + i * 16 + quad * 4;  // aligned 4, no h-crossing
      int hq = od >> 6, d0 = od & 63;
#pragma unroll
      for (int j = 0; j < 4; ++j) {
        int c = n0 + wn + j * 16 + ln;  // global seq 0..4095
        int bb = c >> 11, ns = c & 2047;
        bf16x4 pv;
#pragma unroll
        for (int r = 0; r < 4; ++r) pv[r] = (bf16)(acc[i][j][r] * oscale);
        *(bf16x4*)&out[(((size_t)(bb * NH + hq)) * SEQ + ns) * DH + d0] = pv;
      }
    }
  } else {
#pragma unroll
    for (int i = 0; i < 4; ++i) {
      int sq = m0 + wm + i * 16 + quad * 4;  // aligned 4, no b-crossing
      int bb = sq >> 11, ns0 = sq & 2047;
#pragma unroll
      for (int j = 0; j < 4; ++j) {
        int od = n0 + wn + j * 16 + ln;
        int hq = od >> 6, d = od & 63;
        bf16x4 pv;
#pragma unroll
        for (int r = 0; r < 4; ++r) pv[r] = (bf16)acc[i][j][r];
        *(bf16x4*)&out[(((size_t)(bb * NH + hq)) * DH + d) * SEQ + ns0] = pv;
      }
    }
  }
}

// ---------------------------------------------------------------------------
// Kernel C: flash v7 — v5 compute core (32x32 MFMA, in-reg P, padded-72 LDS,
// reg-staged cache-friendly loads) at HALF the LDS: single-buffered K/V
// (73.7KB) -> 2 blocks/CU = 32 waves/CU cap. 16 waves = 4 qg x 4 splits;
// each wave: 32 q x 512 keys, 8x 64-key tiles. 2 barriers/tile (m97 regime,
// covered by 2 co-resident blocks); T14 prefetch-to-reg after stage barrier.
// launch_bounds(1024,8) pins VGPR<=64 (v5 measured exactly 64).
// ---------------------------------------------------------------------------
__global__ __launch_bounds__(1024, 8) void flash(
    const bf16* __restrict__ Qg, const bf16* __restrict__ Kg,
    const bf16* __restrict__ Vtg, float* __restrict__ Og) {
  // Ks[4 split][64 key][72] = 36864 B | Vs[4 split][64 d][72] = 36864 B
  __shared__ __align__(16) char smem[73728];
  bf16* Ks = (bf16*)smem;
  bf16* Vs = (bf16*)(smem + 36864);
  float* Om = (float*)smem;            // merge overlay: [128 q][68] (34816 B)
  float* Lm = (float*)(smem + 34816);  // merge overlay: [4 split][128 q]

  int t = threadIdx.x;
  int lane = t & 63, w = t >> 6;
  int col = lane & 31, hi = lane >> 5;
  int qg = w >> 2, split = w & 3;
  int bh = blockIdx.y;
  int b = bh >> 4, h = bh & 15;
  const bf16* Q = Qg + (size_t)bh * SEQ * DH;
  const bf16* K = Kg + (size_t)bh * SEQ * DH;
  const bf16* Vt = Vtg + (size_t)bh * DH * SEQ;
  int q0 = blockIdx.x * 128 + qg * 32;

  // Q as B-operand (carries QSCALE): lane holds q=col, d = kc*16 + hi*8 + j
  bf16x8 bq[4];
#pragma unroll
  for (int kc = 0; kc < 4; ++kc)
    bq[kc] = *(const bf16x8*)&Q[(size_t)(q0 + col) * DH + kc * 16 + hi * 8];

  f32x16 oacc[2];
#pragma unroll
  for (int m = 0; m < 2; ++m)
#pragma unroll
    for (int r = 0; r < 16; ++r) oacc[m][r] = 0.f;
  float li = 0.f;

  // staging: threads [256*ss, 256*(ss+1)) stage split ss's 64-key tile
  int ss = t >> 8, st = t & 255;
  int kr = st >> 2, kcol = (st & 3) * 16;  // kr: row 0..63; kcol: 16 elems
  const bf16* kg = K + ((size_t)(ss * 512 + kr)) * DH + kcol;
  const bf16* vg = Vt + (size_t)kr * SEQ + ss * 512 + kcol;
  bf16* kl = Ks + ss * 4608 + kr * 72 + kcol;
  bf16* vl = Vs + ss * 4608 + kr * 72 + kcol;

  bf16x8 pk0 = *(const bf16x8*)kg;
  bf16x8 pk1 = *(const bf16x8*)(kg + 8);
  bf16x8 pv0 = *(const bf16x8*)vg;
  bf16x8 pv1 = *(const bf16x8*)(vg + 8);

  const bf16* Kb = Ks + split * 4608;
  const bf16* Vb = Vs + split * 4608;

#pragma unroll 1
  for (int it = 0; it < 8; ++it) {
    __syncthreads();  // previous tile's LDS reads done before overwrite
    *(bf16x8*)kl = pk0;
    *(bf16x8*)(kl + 8) = pk1;
    *(bf16x8*)vl = pv0;
    *(bf16x8*)(vl + 8) = pv1;
    __syncthreads();  // staged data visible

    if (it + 1 < 8) {  // T14: HBM latency hides under compute below
      size_t ko = (size_t)(it + 1) * 64 * DH;
      pk0 = *(const bf16x8*)(kg + ko);
      pk1 = *(const bf16x8*)(kg + ko + 8);
      pv0 = *(const bf16x8*)(vg + (it + 1) * 64);
      pv1 = *(const bf16x8*)(vg + (it + 1) * 64 + 8);
    }

#pragma unroll
    for (int mt = 0; mt < 2; ++mt) {
      // S^T = K.Q^T: D[m=key][n=q]; lane: q=col, key=mt*32+(r&3)+8(r>>2)+4hi
      f32x16 s;
#pragma unroll
      for (int r = 0; r < 16; ++r) s[r] = 0.f;
#pragma unroll
      for (int kc = 0; kc < 4; ++kc) {
        bf16x8 ak = *(const bf16x8*)&Kb[(mt * 32 + col) * 72 + kc * 16 + hi * 8];
        s = __builtin_amdgcn_mfma_f32_32x32x16_bf16(ak, bq[kc], s, 0, 0, 0);
      }
#pragma unroll
      for (int cc = 0; cc < 2; ++cc) {
        int rb = cc * 8;
        float e0 = exp2f(s[rb + 0]), e1 = exp2f(s[rb + 1]);
        float e2 = exp2f(s[rb + 2]), e3 = exp2f(s[rb + 3]);
        float e4 = exp2f(s[rb + 4]), e5 = exp2f(s[rb + 5]);
        float e6 = exp2f(s[rb + 6]), e7 = exp2f(s[rb + 7]);
        li += ((e0 + e1) + (e2 + e3)) + ((e4 + e5) + (e6 + e7));
        // T12: pack + permlane32_swap -> PV B-operand in registers
        unsigned lo0 = pk_bf16(e0, e1), lo1 = pk_bf16(e2, e3);
        unsigned h0 = pk_bf16(e4, e5), h1 = pk_bf16(e6, e7);
        uint2v r02 = __builtin_amdgcn_permlane32_swap(lo0, h0, false, false);
        uint2v r13 = __builtin_amdgcn_permlane32_swap(lo1, h1, false, false);
        uint4v uu;
        uu[0] = r02[0]; uu[1] = r13[0]; uu[2] = r02[1]; uu[3] = r13[1];
        bf16x8 pb = __builtin_bit_cast(bf16x8, uu);  // B[k=key][n=q]

        int c = mt * 2 + cc;  // 16-key chunk within tile
        // O^T += V^T.P^T: A = V^T[d][key], D[m=d][n=q]
        bf16x8 av0 = *(const bf16x8*)&Vb[(col) * 72 + c * 16 + hi * 8];
        bf16x8 av1 = *(const bf16x8*)&Vb[(32 + col) * 72 + c * 16 + hi * 8];
        oacc[0] = __builtin_amdgcn_mfma_f32_32x32x16_bf16(av0, pb, oacc[0], 0, 0, 0);
        oacc[1] = __builtin_amdgcn_mfma_f32_32x32x16_bf16(av1, pb, oacc[1], 0, 0, 0);
      }
    }
  }

  // ---- 4-way split-K merge (exact): O = sum O_s, l = sum l_s ----
  li += __shfl_xor(li, 32, 64);  // l(q=col) for this wave's split
  __syncthreads();  // all K/V LDS reads done before overlay writes
  if (lane < 32) Lm[split * 128 + qg * 32 + col] = li;

#pragma unroll 1
  for (int rs = 1; rs < 4; ++rs) {
    if (split == rs) {
#pragma unroll
      for (int m = 0; m < 2; ++m)
#pragma unroll
        for (int rr = 0; rr < 4; ++rr) {
          floatx4 v4;
#pragma unroll
          for (int j = 0; j < 4; ++j) v4[j] = oacc[m][rr * 4 + j];
          *(floatx4*)&Om[(qg * 32 + col) * 68 + m * 32 + rr * 8 + hi * 4] = v4;
        }
    }
    __syncthreads();
    if (split == 0) {
#pragma unroll
      for (int m = 0; m < 2; ++m)
#pragma unroll
        for (int rr = 0; rr < 4; ++rr) {
          floatx4 v4 =
              *(const floatx4*)&Om[(qg * 32 + col) * 68 + m * 32 + rr * 8 + hi * 4];
#pragma unroll
          for (int j = 0; j < 4; ++j) oacc[m][rr * 4 + j] += v4[j];
        }
    }
    __syncthreads();
  }
  if (split == 0) {
#pragma unroll
    for (int m = 0; m < 2; ++m)
#pragma unroll
      for (int rr = 0; rr < 4; ++rr) {
        floatx4 v4;
#pragma unroll
        for (int j = 0; j < 4; ++j) v4[j] = oacc[m][rr * 4 + j];
        *(floatx4*)&Om[(qg * 32 + col) * 68 + m * 32 + rr * 8 + hi * 4] = v4;
      }
  }
  __syncthreads();

  // coalesced readout: 128 q x 64 d, scale by 1/l, f32x4 stores
#pragma unroll
  for (int rep = 0; rep < 2; ++rep) {
    int idx = rep * 1024 + t;
    int q = idx >> 4, dc = (idx & 15) * 4;
    float lt = Lm[q] + Lm[128 + q] + Lm[256 + q] + Lm[384 + q];
    float inv = 1.0f / lt;
    floatx4 ov = *(const floatx4*)&Om[q * 68 + dc];
    ov[0] *= inv; ov[1] *= inv; ov[2] *= inv; ov[3] *= inv;
    int ns = blockIdx.x * 128 + q;
    *(floatx4*)&Og[((size_t)(b * SEQ + ns)) * EMBED + h * DH + dc] = ov;
  }
}

// ---------------------------------------------------------------------------
// ws (38 MB): q [0,4M) k [4M,8M) vt [8M,12M) wqt..wvt [12M,15M) xb [15M,19M)
// ---------------------------------------------------------------------------
extern "C" void kernel_launch(void* const* d_in, const int* in_sizes, int n_in,
                              void* d_out, int out_size, void* d_ws, size_t ws_size,
                              hipStream_t stream) {
  const int XEL = 2 * 2048 * 1024;
  const float *x, *Wq, *Wk, *Wv;
  if (in_sizes[0] == XEL) {
    x = (const float*)d_in[0];
    Wq = (const float*)d_in[1];
    Wk = (const float*)d_in[2];
    Wv = (const float*)d_in[3];
  } else {
    Wk = (const float*)d_in[0];
    Wq = (const float*)d_in[1];
    Wv = (const float*)d_in[2];
    x = (const float*)d_in[3];
  }
  bf16* ws = (bf16*)d_ws;

  const size_t M1 = 1024 * 1024;
  bf16* q_ws = ws;
  bf16* k_ws = ws + 4 * M1;
  bf16* vt_ws = ws + 8 * M1;
  bf16* wqt = ws + 12 * M1;
  bf16* wkt = ws + 13 * M1;
  bf16* wvt = ws + 14 * M1;
  bf16* xb = ws + 15 * M1;

  prep<<<dim3(256, 4), 256, 0, stream>>>(x, Wq, Wk, Wv, xb, wqt, wkt, wvt);
  qkv3<<<dim3(768), 256, 0, stream>>>(xb, wqt, wkt, wvt, q_ws, k_ws, vt_ws);
  flash<<<dim3(16, 32), 1024, 0, stream>>>(q_ws, k_ws, vt_ws, (float*)d_out);
}

// Round 6
// 170.203 us; speedup vs baseline: 4.4264x; 4.4264x over previous
//
#include <hip/hip_runtime.h>
#include <cstdint>

typedef __bf16 bf16;
typedef __bf16 bf16x4 __attribute__((ext_vector_type(4)));
typedef __bf16 bf16x8 __attribute__((ext_vector_type(8)));
typedef float floatx4 __attribute__((ext_vector_type(4)));

typedef const __attribute__((address_space(1))) void* as1_cvptr;
typedef __attribute__((address_space(3))) void* as3_vptr;

__device__ __forceinline__ void gl_lds16(const void* g, void* l) {
  __builtin_amdgcn_global_load_lds((as1_cvptr)(uintptr_t)g,
                                   (as3_vptr)(uint32_t)(uintptr_t)l, 16, 0, 0);
}

#define EMBED 1024
#define SEQ 2048
#define NH 16
#define DH 64
// softmax scale folded into Q at projection time: 0.125 * log2(e)
#define QSCALE 0.18033688f

// ---------------------------------------------------------------------------
// Kernel A: prep — grid (256,4). z<3: transpose+downcast W z; z=3: x->bf16.
// ---------------------------------------------------------------------------
__global__ __launch_bounds__(256) void prep(
    const float* __restrict__ x, const float* __restrict__ Wq,
    const float* __restrict__ Wk, const float* __restrict__ Wv,
    bf16* __restrict__ xb, bf16* __restrict__ Wqt,
    bf16* __restrict__ Wkt, bf16* __restrict__ Wvt) {
  __shared__ __align__(16) bf16 tile[64][72];
  int z = blockIdx.y;
  int t = threadIdx.x;
  if (z == 3) {
    size_t base = ((size_t)blockIdx.x * 256 + t) * 8;
#pragma unroll
    for (int it = 0; it < 8; ++it) {
      size_t i = base + (size_t)it * (256 * 256 * 8);
      floatx4 a = *(const floatx4*)(x + i);
      floatx4 bv = *(const floatx4*)(x + i + 4);
      bf16x8 o;
#pragma unroll
      for (int j = 0; j < 4; ++j) { o[j] = (bf16)a[j]; o[4 + j] = (bf16)bv[j]; }
      *(bf16x8*)(xb + i) = o;
    }
    return;
  }
  const float* W = (z == 0) ? Wq : (z == 1) ? Wk : Wv;
  bf16* Wt = (z == 0) ? Wqt : (z == 1) ? Wkt : Wvt;
  int k0 = (blockIdx.x >> 4) * 64, n0 = (blockIdx.x & 15) * 64;
  int r = t >> 3, c = (t & 7) * 8;
#pragma unroll
  for (int half = 0; half < 2; ++half) {
    const float* src = &W[(size_t)(k0 + r + half * 32) * EMBED + n0 + c];
    floatx4 f0 = *(const floatx4*)src;
    floatx4 f1 = *(const floatx4*)(src + 4);
    bf16x8 o;
#pragma unroll
    for (int j = 0; j < 4; ++j) { o[j] = (bf16)f0[j]; o[4 + j] = (bf16)f1[j]; }
    *(bf16x8*)&tile[r + half * 32][c] = o;
  }
  __syncthreads();
#pragma unroll
  for (int p = 0; p < 2; ++p) {
    int nn = (t >> 3) + p * 32, kk = (t & 7) * 8;
    bf16x8 v;
#pragma unroll
    for (int i = 0; i < 8; ++i) v[i] = tile[kk + i][nn];
    *(bf16x8*)&Wt[(size_t)(n0 + nn) * EMBED + k0 + kk] = v;
  }
}

// ---------------------------------------------------------------------------
// Kernel B v2: fused QKV projection. Operand order chosen per z so C rows =
// output's fastest dim -> packed bf16x4 (8B) stores.
// ---------------------------------------------------------------------------
__global__ __launch_bounds__(256) void qkv3(
    const bf16* __restrict__ Xb, const bf16* __restrict__ Wqt,
    const bf16* __restrict__ Wkt, const bf16* __restrict__ Wvt,
    bf16* __restrict__ qo, bf16* __restrict__ ko, bf16* __restrict__ vto) {
  __shared__ __align__(16) bf16 As[128 * 32];
  __shared__ __align__(16) bf16 Bs[128 * 32];

  int gid = blockIdx.x;
  int z = gid % 3;
  int rem = gid / 3;
  int bxx = rem & 7, byy = rem >> 3;  // bxx: outdim tile (8), byy: seq tile (32)

  const bf16* Wt = (z == 0) ? Wqt : (z == 1) ? Wkt : Wvt;
  bf16* out = (z == 0) ? qo : (z == 1) ? ko : vto;
  int m0 = (z == 2 ? byy : bxx) * 128;
  int n0 = (z == 2 ? bxx : byy) * 128;
  const bf16* Asrc = (z == 2) ? Xb : Wt;
  const bf16* Bsrc = (z == 2) ? Wt : Xb;
  float oscale = (z == 0) ? QSCALE : 1.0f;

  int t = threadIdx.x;
  int w = t >> 6, lane = t & 63, ln = lane & 15, quad = lane >> 4;
  int wm = (w >> 1) * 64, wn = (w & 1) * 64;

  floatx4 acc[4][4];
#pragma unroll
  for (int i = 0; i < 4; ++i)
#pragma unroll
    for (int j = 0; j < 4; ++j) acc[i][j] = floatx4{0.f, 0.f, 0.f, 0.f};

  int sr = t >> 2, sc = (t & 3) * 8;
  const bf16* ag = Asrc + (size_t)(m0 + sr) * EMBED + sc;
  const bf16* bg = Bsrc + (size_t)(n0 + sr) * EMBED + sc;
  bf16* al = As + sr * 32 + sc;
  bf16* bl = Bs + sr * 32 + sc;

  for (int k0 = 0; k0 < EMBED; k0 += 32) {
    __syncthreads();
    gl_lds16(ag + k0, al);
    gl_lds16(ag + k0 + (size_t)64 * EMBED, al + 64 * 32);
    gl_lds16(bg + k0, bl);
    gl_lds16(bg + k0 + (size_t)64 * EMBED, bl + 64 * 32);
    __syncthreads();

    bf16x8 afr[4], bfr[4];
#pragma unroll
    for (int i = 0; i < 4; ++i)
      afr[i] = *(const bf16x8*)&As[(wm + i * 16 + ln) * 32 + quad * 8];
#pragma unroll
    for (int j = 0; j < 4; ++j)
      bfr[j] = *(const bf16x8*)&Bs[(wn + j * 16 + ln) * 32 + quad * 8];
#pragma unroll
    for (int i = 0; i < 4; ++i)
#pragma unroll
      for (int j = 0; j < 4; ++j)
        acc[i][j] =
            __builtin_amdgcn_mfma_f32_16x16x32_bf16(afr[i], bfr[j], acc[i][j], 0, 0, 0);
  }

  // Epilogue: C/D 16x16 layout col=lane&15, row=quad*4+r (rows consecutive)
  if (z != 2) {
#pragma unroll
    for (int i = 0; i < 4; ++i) {
      int od = m0 + wm + i * 16 + quad * 4;  // aligned 4, no h-crossing
      int hq = od >> 6, d0 = od & 63;
#pragma unroll
      for (int j = 0; j < 4; ++j) {
        int c = n0 + wn + j * 16 + ln;  // global seq 0..4095
        int bb = c >> 11, ns = c & 2047;
        bf16x4 pv;
#pragma unroll
        for (int r = 0; r < 4; ++r) pv[r] = (bf16)(acc[i][j][r] * oscale);
        *(bf16x4*)&out[(((size_t)(bb * NH + hq)) * SEQ + ns) * DH + d0] = pv;
      }
    }
  } else {
#pragma unroll
    for (int i = 0; i < 4; ++i) {
      int sq = m0 + wm + i * 16 + quad * 4;  // aligned 4, no b-crossing
      int bb = sq >> 11, ns0 = sq & 2047;
#pragma unroll
      for (int j = 0; j < 4; ++j) {
        int od = n0 + wn + j * 16 + ln;
        int hq = od >> 6, d = od & 63;
        bf16x4 pv;
#pragma unroll
        for (int r = 0; r < 4; ++r) pv[r] = (bf16)acc[i][j][r];
        *(bf16x4*)&out[(((size_t)(bb * NH + hq)) * DH + d) * SEQ + ns0] = pv;
      }
    }
  }
}

// ---------------------------------------------------------------------------
// Kernel C: flash v8 — round-0 structure (measured 69.4us, VGPR 32,
// occupancy 66%) with ONE change: conflict-free staging mapping.
// Old: kr=st>>3, kcol=(st&7)*8 (16B K + 16B V per thread) -> 8-way bank
// conflict on every staging ds_write_b128 (1.15e7 conflict cycles).
// New (v5's mapping, measured 65K): each thread stages 32B of EITHER K or
// V: ar=st>>8 picks array, kr=j>>2, kcol=(j&3)*16 -> consecutive 8-lane
// phases hit 8 distinct banks. Same instr & register count.
// 1024 thr / 16 waves: 8 q-groups x 2 key-halves; wave: 16q x 1024 keys.
// S^T formulation; no-max softmax => exact split-K merge (O=O0+O1, l=l0+l1).
// ---------------------------------------------------------------------------
__global__ __launch_bounds__(1024, 8) void flash(
    const bf16* __restrict__ Qg, const bf16* __restrict__ Kg,
    const bf16* __restrict__ Vtg, float* __restrict__ Og) {
  __shared__ __align__(16) char smem[73728];
  bf16* Ks = (bf16*)smem;                  // [2][64][72]
  bf16* Vs = (bf16*)(smem + 18432);        // [2][64][72]  (V^T: [d][key])
  bf16* Ps = (bf16*)(smem + 36864);        // [16 waves][16][72]
  float* Om = (float*)smem;                // merge overlay: [128 q][68]
  float* Lm = (float*)(smem + 34816);      // merge overlay: [2][128]

  int t = threadIdx.x, w = t >> 6, lane = t & 63, ln = lane & 15, quad = lane >> 4;
  int qg = w >> 1, half = w & 1;
  int bh = blockIdx.y;
  int b = bh >> 4, h = bh & 15;
  const bf16* Q = Qg + (size_t)bh * SEQ * DH;
  const bf16* K = Kg + (size_t)bh * SEQ * DH;
  const bf16* Vt = Vtg + (size_t)bh * DH * SEQ;
  int q0 = blockIdx.x * 128 + qg * 16;

  // Q as B-operand: B[n=q(ln)][k=d(quad*8+j)] — Q already carries QSCALE
  bf16x8 bq[2];
#pragma unroll
  for (int kc = 0; kc < 2; ++kc)
    bq[kc] = *(const bf16x8*)&Q[(size_t)(q0 + ln) * DH + kc * 32 + quad * 8];

  floatx4 oacc[4];
  float li = 0.f;
#pragma unroll
  for (int dt = 0; dt < 4; ++dt) oacc[dt] = floatx4{0.f, 0.f, 0.f, 0.f};

  // staging roles: threads [0,512) stage half 0's tiles, [512,1024) half 1's.
  // Within a half: j<256 -> K (32B/thread), j>=256 -> V (32B/thread).
  int sh = t >> 9, st = t & 511;
  int ar = st >> 8, j = st & 255;
  int kr = j >> 2, kcol = (j & 3) * 16;  // row 0..63, 32B col chunk
  const bf16* gsrc;
  bf16* ldst;
  int gstep;
  if (ar == 0) {
    gsrc = K + (size_t)(sh * 1024 + kr) * DH + kcol;   // K row kr, d-chunk
    ldst = Ks + sh * 4608 + kr * 72 + kcol;
    gstep = 64 * DH;                                   // 64 keys per tile
  } else {
    gsrc = Vt + (size_t)kr * SEQ + sh * 1024 + kcol;   // V^T d=kr, key-chunk
    ldst = Vs + sh * 4608 + kr * 72 + kcol;
    gstep = 64;                                        // 64 keys per tile
  }

  bf16x8 p0 = *(const bf16x8*)gsrc;
  bf16x8 p1 = *(const bf16x8*)(gsrc + 8);

  const bf16* Ksh = Ks + half * 4608;
  const bf16* Vsh = Vs + half * 4608;
  bf16* Pw = Ps + w * (16 * 72);

  for (int it = 0; it < 16; ++it) {
    __syncthreads();
    *(bf16x8*)ldst = p0;
    *(bf16x8*)(ldst + 8) = p1;
    __syncthreads();

    if (it + 1 < 16) {
      const bf16* gnext = gsrc + (size_t)(it + 1) * gstep;
      p0 = *(const bf16x8*)gnext;
      p1 = *(const bf16x8*)(gnext + 8);
    }

    // S^T = K.Q^T: D[m=key][n=q]; s[nt][r] = score(q=ln, key=nt*16+quad*4+r)
    floatx4 s[4];
#pragma unroll
    for (int nt = 0; nt < 4; ++nt) s[nt] = floatx4{0.f, 0.f, 0.f, 0.f};
#pragma unroll
    for (int kc = 0; kc < 2; ++kc) {
#pragma unroll
      for (int nt = 0; nt < 4; ++nt) {
        bf16x8 ak = *(const bf16x8*)&Ksh[(nt * 16 + ln) * 72 + kc * 32 + quad * 8];
        s[nt] = __builtin_amdgcn_mfma_f32_16x16x32_bf16(ak, bq[kc], s[nt], 0, 0, 0);
      }
    }

    // p = exp2(s) (scale pre-folded into Q); packed b64 P writes; per-lane li
#pragma unroll
    for (int nt = 0; nt < 4; ++nt) {
      float p0f = exp2f(s[nt][0]);
      float p1f = exp2f(s[nt][1]);
      float p2f = exp2f(s[nt][2]);
      float p3f = exp2f(s[nt][3]);
      li += (p0f + p1f) + (p2f + p3f);
      bf16x4 pq = {(bf16)p0f, (bf16)p1f, (bf16)p2f, (bf16)p3f};
      *(bf16x4*)&Pw[ln * 72 + nt * 16 + quad * 4] = pq;
    }

    // O += P.V: A = P[q][key] (m=q), B = V^T[d][key] (n=d); same-wave LDS order
#pragma unroll
    for (int kc2 = 0; kc2 < 2; ++kc2) {
      bf16x8 ap = *(const bf16x8*)&Pw[ln * 72 + kc2 * 32 + quad * 8];
#pragma unroll
      for (int dt = 0; dt < 4; ++dt) {
        bf16x8 bv = *(const bf16x8*)&Vsh[(dt * 16 + ln) * 72 + kc2 * 32 + quad * 8];
        oacc[dt] = __builtin_amdgcn_mfma_f32_16x16x32_bf16(ap, bv, oacc[dt], 0, 0, 0);
      }
    }
  }

  // ---- split-K merge: O = O_half0 + O_half1, l = l0 + l1 (exact) ----
  __syncthreads();  // all compute (and last-tile LDS reads) done; reuse smem
  li += __shfl_xor(li, 16, 64);
  li += __shfl_xor(li, 32, 64);   // all lanes: li(q=ln) for this wave's half
  if (quad == 0) Lm[half * 128 + qg * 16 + ln] = li;
  if (half) {
#pragma unroll
    for (int r = 0; r < 4; ++r) {
      int q = qg * 16 + quad * 4 + r;
#pragma unroll
      for (int dt = 0; dt < 4; ++dt) Om[q * 68 + dt * 16 + ln] = oacc[dt][r];
    }
  }
  __syncthreads();
  if (!half) {
#pragma unroll
    for (int r = 0; r < 4; ++r) {
      int qq = qg * 16 + quad * 4 + r;
      float lt = Lm[qq] + Lm[128 + qq];
      float inv = 1.0f / lt;
      int ns = blockIdx.x * 128 + qq;
#pragma unroll
      for (int dt = 0; dt < 4; ++dt) {
        int d = dt * 16 + ln;
        float val = (oacc[dt][r] + Om[qq * 68 + d]) * inv;
        Og[((size_t)(b * SEQ + ns)) * EMBED + h * DH + d] = val;
      }
    }
  }
}

// ---------------------------------------------------------------------------
// ws (38 MB): q [0,4M) k [4M,8M) vt [8M,12M) wqt..wvt [12M,15M) xb [15M,19M)
// ---------------------------------------------------------------------------
extern "C" void kernel_launch(void* const* d_in, const int* in_sizes, int n_in,
                              void* d_out, int out_size, void* d_ws, size_t ws_size,
                              hipStream_t stream) {
  const int XEL = 2 * 2048 * 1024;
  const float *x, *Wq, *Wk, *Wv;
  if (in_sizes[0] == XEL) {
    x = (const float*)d_in[0];
    Wq = (const float*)d_in[1];
    Wk = (const float*)d_in[2];
    Wv = (const float*)d_in[3];
  } else {
    Wk = (const float*)d_in[0];
    Wq = (const float*)d_in[1];
    Wv = (const float*)d_in[2];
    x = (const float*)d_in[3];
  }
  bf16* ws = (bf16*)d_ws;

  const size_t M1 = 1024 * 1024;
  bf16* q_ws = ws;
  bf16* k_ws = ws + 4 * M1;
  bf16* vt_ws = ws + 8 * M1;
  bf16* wqt = ws + 12 * M1;
  bf16* wkt = ws + 13 * M1;
  bf16* wvt = ws + 14 * M1;
  bf16* xb = ws + 15 * M1;

  prep<<<dim3(256, 4), 256, 0, stream>>>(x, Wq, Wk, Wv, xb, wqt, wkt, wvt);
  qkv3<<<dim3(768), 256, 0, stream>>>(xb, wqt, wkt, wvt, q_ws, k_ws, vt_ws);
  flash<<<dim3(16, 32), 1024, 0, stream>>>(q_ws, k_ws, vt_ws, (float*)d_out);
}

// Round 7
// 170.153 us; speedup vs baseline: 4.4277x; 1.0003x over previous
//
#include <hip/hip_runtime.h>
#include <cstdint>

typedef __bf16 bf16;
typedef __bf16 bf16x4 __attribute__((ext_vector_type(4)));
typedef __bf16 bf16x8 __attribute__((ext_vector_type(8)));
typedef float floatx4 __attribute__((ext_vector_type(4)));

typedef const __attribute__((address_space(1))) void* as1_cvptr;
typedef __attribute__((address_space(3))) void* as3_vptr;

__device__ __forceinline__ void gl_lds16(const void* g, void* l) {
  __builtin_amdgcn_global_load_lds((as1_cvptr)(uintptr_t)g,
                                   (as3_vptr)(uint32_t)(uintptr_t)l, 16, 0, 0);
}

#define EMBED 1024
#define SEQ 2048
#define NH 16
#define DH 64
// softmax scale folded into Q at projection time: 0.125 * log2(e)
#define QSCALE 0.18033688f

// ---------------------------------------------------------------------------
// Kernel A: prep — grid (256,4). z<3: transpose+downcast W z; z=3: x->bf16.
// ---------------------------------------------------------------------------
__global__ __launch_bounds__(256) void prep(
    const float* __restrict__ x, const float* __restrict__ Wq,
    const float* __restrict__ Wk, const float* __restrict__ Wv,
    bf16* __restrict__ xb, bf16* __restrict__ Wqt,
    bf16* __restrict__ Wkt, bf16* __restrict__ Wvt) {
  __shared__ __align__(16) bf16 tile[64][72];
  int z = blockIdx.y;
  int t = threadIdx.x;
  if (z == 3) {
    size_t base = ((size_t)blockIdx.x * 256 + t) * 8;
#pragma unroll
    for (int it = 0; it < 8; ++it) {
      size_t i = base + (size_t)it * (256 * 256 * 8);
      floatx4 a = *(const floatx4*)(x + i);
      floatx4 bv = *(const floatx4*)(x + i + 4);
      bf16x8 o;
#pragma unroll
      for (int j = 0; j < 4; ++j) { o[j] = (bf16)a[j]; o[4 + j] = (bf16)bv[j]; }
      *(bf16x8*)(xb + i) = o;
    }
    return;
  }
  const float* W = (z == 0) ? Wq : (z == 1) ? Wk : Wv;
  bf16* Wt = (z == 0) ? Wqt : (z == 1) ? Wkt : Wvt;
  int k0 = (blockIdx.x >> 4) * 64, n0 = (blockIdx.x & 15) * 64;
  int r = t >> 3, c = (t & 7) * 8;
#pragma unroll
  for (int half = 0; half < 2; ++half) {
    const float* src = &W[(size_t)(k0 + r + half * 32) * EMBED + n0 + c];
    floatx4 f0 = *(const floatx4*)src;
    floatx4 f1 = *(const floatx4*)(src + 4);
    bf16x8 o;
#pragma unroll
    for (int j = 0; j < 4; ++j) { o[j] = (bf16)f0[j]; o[4 + j] = (bf16)f1[j]; }
    *(bf16x8*)&tile[r + half * 32][c] = o;
  }
  __syncthreads();
#pragma unroll
  for (int p = 0; p < 2; ++p) {
    int nn = (t >> 3) + p * 32, kk = (t & 7) * 8;
    bf16x8 v;
#pragma unroll
    for (int i = 0; i < 8; ++i) v[i] = tile[kk + i][nn];
    *(bf16x8*)&Wt[(size_t)(n0 + nn) * EMBED + k0 + kk] = v;
  }
}

// ---------------------------------------------------------------------------
// Kernel B v3: fused QKV projection — 2-phase double-buffered prefetch
// (T3-minimum): stage K-step t+1 into buf^1 BEFORE computing step t from
// buf; ONE __syncthreads per step (was 2). HBM latency of the stage flies
// under the MFMA phase instead of being serially drained every step.
// Race safety: reads of buf[cur] at step t are drained by t's syncthreads
// (vm+lgkm) before any wave issues the t+2 stage that overwrites it.
// LDS 2x16KB = 32KB. Epilogue: packed bf16x4 stores (C rows = fastest dim).
// ---------------------------------------------------------------------------
__global__ __launch_bounds__(256) void qkv3(
    const bf16* __restrict__ Xb, const bf16* __restrict__ Wqt,
    const bf16* __restrict__ Wkt, const bf16* __restrict__ Wvt,
    bf16* __restrict__ qo, bf16* __restrict__ ko, bf16* __restrict__ vto) {
  __shared__ __align__(16) bf16 As[2][128 * 32];
  __shared__ __align__(16) bf16 Bs[2][128 * 32];

  int gid = blockIdx.x;
  int z = gid % 3;
  int rem = gid / 3;
  int bxx = rem & 7, byy = rem >> 3;  // bxx: outdim tile (8), byy: seq tile (32)

  const bf16* Wt = (z == 0) ? Wqt : (z == 1) ? Wkt : Wvt;
  bf16* out = (z == 0) ? qo : (z == 1) ? ko : vto;
  int m0 = (z == 2 ? byy : bxx) * 128;
  int n0 = (z == 2 ? bxx : byy) * 128;
  const bf16* Asrc = (z == 2) ? Xb : Wt;
  const bf16* Bsrc = (z == 2) ? Wt : Xb;
  float oscale = (z == 0) ? QSCALE : 1.0f;

  int t = threadIdx.x;
  int w = t >> 6, lane = t & 63, ln = lane & 15, quad = lane >> 4;
  int wm = (w >> 1) * 64, wn = (w & 1) * 64;

  floatx4 acc[4][4];
#pragma unroll
  for (int i = 0; i < 4; ++i)
#pragma unroll
    for (int j = 0; j < 4; ++j) acc[i][j] = floatx4{0.f, 0.f, 0.f, 0.f};

  int sr = t >> 2, sc = (t & 3) * 8;
  const bf16* ag = Asrc + (size_t)(m0 + sr) * EMBED + sc;
  const bf16* bg = Bsrc + (size_t)(n0 + sr) * EMBED + sc;
  int so = sr * 32 + sc;

  // prologue: stage k-step 0 into buffer 0
  gl_lds16(ag, &As[0][so]);
  gl_lds16(ag + (size_t)64 * EMBED, &As[0][so + 64 * 32]);
  gl_lds16(bg, &Bs[0][so]);
  gl_lds16(bg + (size_t)64 * EMBED, &Bs[0][so + 64 * 32]);
  __syncthreads();

  for (int ks = 0; ks < 32; ++ks) {
    int cur = ks & 1, nxt = cur ^ 1;
    if (ks + 1 < 32) {  // issue next tile's loads BEFORE compute (prefetch)
      int k0 = (ks + 1) * 32;
      gl_lds16(ag + k0, &As[nxt][so]);
      gl_lds16(ag + k0 + (size_t)64 * EMBED, &As[nxt][so + 64 * 32]);
      gl_lds16(bg + k0, &Bs[nxt][so]);
      gl_lds16(bg + k0 + (size_t)64 * EMBED, &Bs[nxt][so + 64 * 32]);
    }
    const bf16* Ac = As[cur];
    const bf16* Bc = Bs[cur];
    bf16x8 afr[4], bfr[4];
#pragma unroll
    for (int i = 0; i < 4; ++i)
      afr[i] = *(const bf16x8*)&Ac[(wm + i * 16 + ln) * 32 + quad * 8];
#pragma unroll
    for (int j = 0; j < 4; ++j)
      bfr[j] = *(const bf16x8*)&Bc[(wn + j * 16 + ln) * 32 + quad * 8];
#pragma unroll
    for (int i = 0; i < 4; ++i)
#pragma unroll
      for (int j = 0; j < 4; ++j)
        acc[i][j] =
            __builtin_amdgcn_mfma_f32_16x16x32_bf16(afr[i], bfr[j], acc[i][j], 0, 0, 0);
    __syncthreads();  // drains my stage loads (vm) + all waves' reads (lgkm)
  }

  // Epilogue: C/D 16x16 layout col=lane&15, row=quad*4+r (rows consecutive)
  if (z != 2) {
#pragma unroll
    for (int i = 0; i < 4; ++i) {
      int od = m0 + wm + i * 16 + quad * 4;  // aligned 4, no h-crossing
      int hq = od >> 6, d0 = od & 63;
#pragma unroll
      for (int j = 0; j < 4; ++j) {
        int c = n0 + wn + j * 16 + ln;  // global seq 0..4095
        int bb = c >> 11, ns = c & 2047;
        bf16x4 pv;
#pragma unroll
        for (int r = 0; r < 4; ++r) pv[r] = (bf16)(acc[i][j][r] * oscale);
        *(bf16x4*)&out[(((size_t)(bb * NH + hq)) * SEQ + ns) * DH + d0] = pv;
      }
    }
  } else {
#pragma unroll
    for (int i = 0; i < 4; ++i) {
      int sq = m0 + wm + i * 16 + quad * 4;  // aligned 4, no b-crossing
      int bb = sq >> 11, ns0 = sq & 2047;
#pragma unroll
      for (int j = 0; j < 4; ++j) {
        int od = n0 + wn + j * 16 + ln;
        int hq = od >> 6, d = od & 63;
        bf16x4 pv;
#pragma unroll
        for (int r = 0; r < 4; ++r) pv[r] = (bf16)acc[i][j][r];
        *(bf16x4*)&out[(((size_t)(bb * NH + hq)) * DH + d) * SEQ + ns0] = pv;
      }
    }
  }
}

// ---------------------------------------------------------------------------
// Kernel C: flash v8 (unchanged from round 6 — 67.2us measured).
// 1024 thr / 16 waves: 8 q-groups x 2 key-halves; wave: 16q x 1024 keys.
// S^T formulation; no-max softmax => exact split-K merge (O=O0+O1, l=l0+l1).
// ---------------------------------------------------------------------------
__global__ __launch_bounds__(1024, 8) void flash(
    const bf16* __restrict__ Qg, const bf16* __restrict__ Kg,
    const bf16* __restrict__ Vtg, float* __restrict__ Og) {
  __shared__ __align__(16) char smem[73728];
  bf16* Ks = (bf16*)smem;                  // [2][64][72]
  bf16* Vs = (bf16*)(smem + 18432);        // [2][64][72]  (V^T: [d][key])
  bf16* Ps = (bf16*)(smem + 36864);        // [16 waves][16][72]
  float* Om = (float*)smem;                // merge overlay: [128 q][68]
  float* Lm = (float*)(smem + 34816);      // merge overlay: [2][128]

  int t = threadIdx.x, w = t >> 6, lane = t & 63, ln = lane & 15, quad = lane >> 4;
  int qg = w >> 1, half = w & 1;
  int bh = blockIdx.y;
  int b = bh >> 4, h = bh & 15;
  const bf16* Q = Qg + (size_t)bh * SEQ * DH;
  const bf16* K = Kg + (size_t)bh * SEQ * DH;
  const bf16* Vt = Vtg + (size_t)bh * DH * SEQ;
  int q0 = blockIdx.x * 128 + qg * 16;

  // Q as B-operand: B[n=q(ln)][k=d(quad*8+j)] — Q already carries QSCALE
  bf16x8 bq[2];
#pragma unroll
  for (int kc = 0; kc < 2; ++kc)
    bq[kc] = *(const bf16x8*)&Q[(size_t)(q0 + ln) * DH + kc * 32 + quad * 8];

  floatx4 oacc[4];
  float li = 0.f;
#pragma unroll
  for (int dt = 0; dt < 4; ++dt) oacc[dt] = floatx4{0.f, 0.f, 0.f, 0.f};

  // staging roles: threads [0,512) stage half 0's tiles, [512,1024) half 1's.
  // Within a half: j<256 -> K (32B/thread), j>=256 -> V (32B/thread).
  int sh = t >> 9, st = t & 511;
  int ar = st >> 8, j = st & 255;
  int kr = j >> 2, kcol = (j & 3) * 16;  // row 0..63, 32B col chunk
  const bf16* gsrc;
  bf16* ldst;
  int gstep;
  if (ar == 0) {
    gsrc = K + (size_t)(sh * 1024 + kr) * DH + kcol;   // K row kr, d-chunk
    ldst = Ks + sh * 4608 + kr * 72 + kcol;
    gstep = 64 * DH;                                   // 64 keys per tile
  } else {
    gsrc = Vt + (size_t)kr * SEQ + sh * 1024 + kcol;   // V^T d=kr, key-chunk
    ldst = Vs + sh * 4608 + kr * 72 + kcol;
    gstep = 64;                                        // 64 keys per tile
  }

  bf16x8 p0 = *(const bf16x8*)gsrc;
  bf16x8 p1 = *(const bf16x8*)(gsrc + 8);

  const bf16* Ksh = Ks + half * 4608;
  const bf16* Vsh = Vs + half * 4608;
  bf16* Pw = Ps + w * (16 * 72);

  for (int it = 0; it < 16; ++it) {
    __syncthreads();
    *(bf16x8*)ldst = p0;
    *(bf16x8*)(ldst + 8) = p1;
    __syncthreads();

    if (it + 1 < 16) {
      const bf16* gnext = gsrc + (size_t)(it + 1) * gstep;
      p0 = *(const bf16x8*)gnext;
      p1 = *(const bf16x8*)(gnext + 8);
    }

    // S^T = K.Q^T: D[m=key][n=q]; s[nt][r] = score(q=ln, key=nt*16+quad*4+r)
    floatx4 s[4];
#pragma unroll
    for (int nt = 0; nt < 4; ++nt) s[nt] = floatx4{0.f, 0.f, 0.f, 0.f};
#pragma unroll
    for (int kc = 0; kc < 2; ++kc) {
#pragma unroll
      for (int nt = 0; nt < 4; ++nt) {
        bf16x8 ak = *(const bf16x8*)&Ksh[(nt * 16 + ln) * 72 + kc * 32 + quad * 8];
        s[nt] = __builtin_amdgcn_mfma_f32_16x16x32_bf16(ak, bq[kc], s[nt], 0, 0, 0);
      }
    }

    // p = exp2(s) (scale pre-folded into Q); packed b64 P writes; per-lane li
#pragma unroll
    for (int nt = 0; nt < 4; ++nt) {
      float p0f = exp2f(s[nt][0]);
      float p1f = exp2f(s[nt][1]);
      float p2f = exp2f(s[nt][2]);
      float p3f = exp2f(s[nt][3]);
      li += (p0f + p1f) + (p2f + p3f);
      bf16x4 pq = {(bf16)p0f, (bf16)p1f, (bf16)p2f, (bf16)p3f};
      *(bf16x4*)&Pw[ln * 72 + nt * 16 + quad * 4] = pq;
    }

    // O += P.V: A = P[q][key] (m=q), B = V^T[d][key] (n=d); same-wave LDS order
#pragma unroll
    for (int kc2 = 0; kc2 < 2; ++kc2) {
      bf16x8 ap = *(const bf16x8*)&Pw[ln * 72 + kc2 * 32 + quad * 8];
#pragma unroll
      for (int dt = 0; dt < 4; ++dt) {
        bf16x8 bv = *(const bf16x8*)&Vsh[(dt * 16 + ln) * 72 + kc2 * 32 + quad * 8];
        oacc[dt] = __builtin_amdgcn_mfma_f32_16x16x32_bf16(ap, bv, oacc[dt], 0, 0, 0);
      }
    }
  }

  // ---- split-K merge: O = O_half0 + O_half1, l = l0 + l1 (exact) ----
  __syncthreads();  // all compute (and last-tile LDS reads) done; reuse smem
  li += __shfl_xor(li, 16, 64);
  li += __shfl_xor(li, 32, 64);   // all lanes: li(q=ln) for this wave's half
  if (quad == 0) Lm[half * 128 + qg * 16 + ln] = li;
  if (half) {
#pragma unroll
    for (int r = 0; r < 4; ++r) {
      int q = qg * 16 + quad * 4 + r;
#pragma unroll
      for (int dt = 0; dt < 4; ++dt) Om[q * 68 + dt * 16 + ln] = oacc[dt][r];
    }
  }
  __syncthreads();
  if (!half) {
#pragma unroll
    for (int r = 0; r < 4; ++r) {
      int qq = qg * 16 + quad * 4 + r;
      float lt = Lm[qq] + Lm[128 + qq];
      float inv = 1.0f / lt;
      int ns = blockIdx.x * 128 + qq;
#pragma unroll
      for (int dt = 0; dt < 4; ++dt) {
        int d = dt * 16 + ln;
        float val = (oacc[dt][r] + Om[qq * 68 + d]) * inv;
        Og[((size_t)(b * SEQ + ns)) * EMBED + h * DH + d] = val;
      }
    }
  }
}

// ---------------------------------------------------------------------------
// ws (38 MB): q [0,4M) k [4M,8M) vt [8M,12M) wqt..wvt [12M,15M) xb [15M,19M)
// ---------------------------------------------------------------------------
extern "C" void kernel_launch(void* const* d_in, const int* in_sizes, int n_in,
                              void* d_out, int out_size, void* d_ws, size_t ws_size,
                              hipStream_t stream) {
  const int XEL = 2 * 2048 * 1024;
  const float *x, *Wq, *Wk, *Wv;
  if (in_sizes[0] == XEL) {
    x = (const float*)d_in[0];
    Wq = (const float*)d_in[1];
    Wk = (const float*)d_in[2];
    Wv = (const float*)d_in[3];
  } else {
    Wk = (const float*)d_in[0];
    Wq = (const float*)d_in[1];
    Wv = (const float*)d_in[2];
    x = (const float*)d_in[3];
  }
  bf16* ws = (bf16*)d_ws;

  const size_t M1 = 1024 * 1024;
  bf16* q_ws = ws;
  bf16* k_ws = ws + 4 * M1;
  bf16* vt_ws = ws + 8 * M1;
  bf16* wqt = ws + 12 * M1;
  bf16* wkt = ws + 13 * M1;
  bf16* wvt = ws + 14 * M1;
  bf16* xb = ws + 15 * M1;

  prep<<<dim3(256, 4), 256, 0, stream>>>(x, Wq, Wk, Wv, xb, wqt, wkt, wvt);
  qkv3<<<dim3(768), 256, 0, stream>>>(xb, wqt, wkt, wvt, q_ws, k_ws, vt_ws);
  flash<<<dim3(16, 32), 1024, 0, stream>>>(q_ws, k_ws, vt_ws, (float*)d_out);
}

// Round 8
// 169.006 us; speedup vs baseline: 4.4577x; 1.0068x over previous
//
#include <hip/hip_runtime.h>
#include <cstdint>

typedef __bf16 bf16;
typedef __bf16 bf16x4 __attribute__((ext_vector_type(4)));
typedef __bf16 bf16x8 __attribute__((ext_vector_type(8)));
typedef float floatx4 __attribute__((ext_vector_type(4)));

typedef const __attribute__((address_space(1))) void* as1_cvptr;
typedef __attribute__((address_space(3))) void* as3_vptr;

__device__ __forceinline__ void gl_lds16(const void* g, void* l) {
  __builtin_amdgcn_global_load_lds((as1_cvptr)(uintptr_t)g,
                                   (as3_vptr)(uint32_t)(uintptr_t)l, 16, 0, 0);
}

#define EMBED 1024
#define SEQ 2048
#define NH 16
#define DH 64
// softmax scale folded into Q at projection time: 0.125 * log2(e)
#define QSCALE 0.18033688f

// ---------------------------------------------------------------------------
// Kernel A: prep — grid (256,4). z<3: transpose+downcast W z; z=3: x->bf16.
// ---------------------------------------------------------------------------
__global__ __launch_bounds__(256) void prep(
    const float* __restrict__ x, const float* __restrict__ Wq,
    const float* __restrict__ Wk, const float* __restrict__ Wv,
    bf16* __restrict__ xb, bf16* __restrict__ Wqt,
    bf16* __restrict__ Wkt, bf16* __restrict__ Wvt) {
  __shared__ __align__(16) bf16 tile[64][72];
  int z = blockIdx.y;
  int t = threadIdx.x;
  if (z == 3) {
    size_t base = ((size_t)blockIdx.x * 256 + t) * 8;
#pragma unroll
    for (int it = 0; it < 8; ++it) {
      size_t i = base + (size_t)it * (256 * 256 * 8);
      floatx4 a = *(const floatx4*)(x + i);
      floatx4 bv = *(const floatx4*)(x + i + 4);
      bf16x8 o;
#pragma unroll
      for (int j = 0; j < 4; ++j) { o[j] = (bf16)a[j]; o[4 + j] = (bf16)bv[j]; }
      *(bf16x8*)(xb + i) = o;
    }
    return;
  }
  const float* W = (z == 0) ? Wq : (z == 1) ? Wk : Wv;
  bf16* Wt = (z == 0) ? Wqt : (z == 1) ? Wkt : Wvt;
  int k0 = (blockIdx.x >> 4) * 64, n0 = (blockIdx.x & 15) * 64;
  int r = t >> 3, c = (t & 7) * 8;
#pragma unroll
  for (int half = 0; half < 2; ++half) {
    const float* src = &W[(size_t)(k0 + r + half * 32) * EMBED + n0 + c];
    floatx4 f0 = *(const floatx4*)src;
    floatx4 f1 = *(const floatx4*)(src + 4);
    bf16x8 o;
#pragma unroll
    for (int j = 0; j < 4; ++j) { o[j] = (bf16)f0[j]; o[4 + j] = (bf16)f1[j]; }
    *(bf16x8*)&tile[r + half * 32][c] = o;
  }
  __syncthreads();
#pragma unroll
  for (int p = 0; p < 2; ++p) {
    int nn = (t >> 3) + p * 32, kk = (t & 7) * 8;
    bf16x8 v;
#pragma unroll
    for (int i = 0; i < 8; ++i) v[i] = tile[kk + i][nn];
    *(bf16x8*)&Wt[(size_t)(n0 + nn) * EMBED + k0 + kk] = v;
  }
}

// ---------------------------------------------------------------------------
// Kernel B v3: fused QKV projection — 2-phase double-buffered prefetch.
// (Measured: structurally at its 2-phase ceiling; unchanged this round.)
// ---------------------------------------------------------------------------
__global__ __launch_bounds__(256) void qkv3(
    const bf16* __restrict__ Xb, const bf16* __restrict__ Wqt,
    const bf16* __restrict__ Wkt, const bf16* __restrict__ Wvt,
    bf16* __restrict__ qo, bf16* __restrict__ ko, bf16* __restrict__ vto) {
  __shared__ __align__(16) bf16 As[2][128 * 32];
  __shared__ __align__(16) bf16 Bs[2][128 * 32];

  int gid = blockIdx.x;
  int z = gid % 3;
  int rem = gid / 3;
  int bxx = rem & 7, byy = rem >> 3;  // bxx: outdim tile (8), byy: seq tile (32)

  const bf16* Wt = (z == 0) ? Wqt : (z == 1) ? Wkt : Wvt;
  bf16* out = (z == 0) ? qo : (z == 1) ? ko : vto;
  int m0 = (z == 2 ? byy : bxx) * 128;
  int n0 = (z == 2 ? bxx : byy) * 128;
  const bf16* Asrc = (z == 2) ? Xb : Wt;
  const bf16* Bsrc = (z == 2) ? Wt : Xb;
  float oscale = (z == 0) ? QSCALE : 1.0f;

  int t = threadIdx.x;
  int w = t >> 6, lane = t & 63, ln = lane & 15, quad = lane >> 4;
  int wm = (w >> 1) * 64, wn = (w & 1) * 64;

  floatx4 acc[4][4];
#pragma unroll
  for (int i = 0; i < 4; ++i)
#pragma unroll
    for (int j = 0; j < 4; ++j) acc[i][j] = floatx4{0.f, 0.f, 0.f, 0.f};

  int sr = t >> 2, sc = (t & 3) * 8;
  const bf16* ag = Asrc + (size_t)(m0 + sr) * EMBED + sc;
  const bf16* bg = Bsrc + (size_t)(n0 + sr) * EMBED + sc;
  int so = sr * 32 + sc;

  // prologue: stage k-step 0 into buffer 0
  gl_lds16(ag, &As[0][so]);
  gl_lds16(ag + (size_t)64 * EMBED, &As[0][so + 64 * 32]);
  gl_lds16(bg, &Bs[0][so]);
  gl_lds16(bg + (size_t)64 * EMBED, &Bs[0][so + 64 * 32]);
  __syncthreads();

  for (int ks = 0; ks < 32; ++ks) {
    int cur = ks & 1, nxt = cur ^ 1;
    if (ks + 1 < 32) {  // issue next tile's loads BEFORE compute (prefetch)
      int k0 = (ks + 1) * 32;
      gl_lds16(ag + k0, &As[nxt][so]);
      gl_lds16(ag + k0 + (size_t)64 * EMBED, &As[nxt][so + 64 * 32]);
      gl_lds16(bg + k0, &Bs[nxt][so]);
      gl_lds16(bg + k0 + (size_t)64 * EMBED, &Bs[nxt][so + 64 * 32]);
    }
    const bf16* Ac = As[cur];
    const bf16* Bc = Bs[cur];
    bf16x8 afr[4], bfr[4];
#pragma unroll
    for (int i = 0; i < 4; ++i)
      afr[i] = *(const bf16x8*)&Ac[(wm + i * 16 + ln) * 32 + quad * 8];
#pragma unroll
    for (int j = 0; j < 4; ++j)
      bfr[j] = *(const bf16x8*)&Bc[(wn + j * 16 + ln) * 32 + quad * 8];
#pragma unroll
    for (int i = 0; i < 4; ++i)
#pragma unroll
      for (int j = 0; j < 4; ++j)
        acc[i][j] =
            __builtin_amdgcn_mfma_f32_16x16x32_bf16(afr[i], bfr[j], acc[i][j], 0, 0, 0);
    __syncthreads();  // drains my stage loads (vm) + all waves' reads (lgkm)
  }

  // Epilogue: C/D 16x16 layout col=lane&15, row=quad*4+r (rows consecutive)
  if (z != 2) {
#pragma unroll
    for (int i = 0; i < 4; ++i) {
      int od = m0 + wm + i * 16 + quad * 4;  // aligned 4, no h-crossing
      int hq = od >> 6, d0 = od & 63;
#pragma unroll
      for (int j = 0; j < 4; ++j) {
        int c = n0 + wn + j * 16 + ln;  // global seq 0..4095
        int bb = c >> 11, ns = c & 2047;
        bf16x4 pv;
#pragma unroll
        for (int r = 0; r < 4; ++r) pv[r] = (bf16)(acc[i][j][r] * oscale);
        *(bf16x4*)&out[(((size_t)(bb * NH + hq)) * SEQ + ns) * DH + d0] = pv;
      }
    }
  } else {
#pragma unroll
    for (int i = 0; i < 4; ++i) {
      int sq = m0 + wm + i * 16 + quad * 4;  // aligned 4, no b-crossing
      int bb = sq >> 11, ns0 = sq & 2047;
#pragma unroll
      for (int j = 0; j < 4; ++j) {
        int od = n0 + wn + j * 16 + ln;
        int hq = od >> 6, d = od & 63;
        bf16x4 pv;
#pragma unroll
        for (int r = 0; r < 4; ++r) pv[r] = (bf16)acc[i][j][r];
        *(bf16x4*)&out[(((size_t)(bb * NH + hq)) * DH + d) * SEQ + ns0] = pv;
      }
    }
  }
}

// ---------------------------------------------------------------------------
// Kernel C: flash v10 — v8 structure + two VALU cuts (VALUBusy 51% is the
// measured limiter):
// (1) raw v_exp_f32 via __builtin_amdgcn_exp2f (scores |s|<~6; drop the libm
//     range-fixup instrs that exp2f emits without fast-math).
// (2) l(q) via MFMA with constant-ones B-frag (matrix pipe at 20% idle):
//     oL = mfma(P, ones, oL) -> D[q][*] = sum_key P; lane holds l(quad*4+r),
//     matching the oacc merge layout. Removes 16 li-adds/iter + end shfl
//     reduce; merge simplified (half1 stores Lm[128]; half0 adds own oL[r]).
// Bank conflicts (1.15e7) understood as benign 2-way aliasing (ln vs ln+8,
// 144B row stride) — cost ~1.02x, not worth breaking.
// ---------------------------------------------------------------------------
__global__ __launch_bounds__(1024, 8) void flash(
    const bf16* __restrict__ Qg, const bf16* __restrict__ Kg,
    const bf16* __restrict__ Vtg, float* __restrict__ Og) {
  __shared__ __align__(16) char smem[73728];
  bf16* Ks = (bf16*)smem;                  // [2][64][72]
  bf16* Vs = (bf16*)(smem + 18432);        // [2][64][72]  (V^T: [d][key])
  bf16* Ps = (bf16*)(smem + 36864);        // [16 waves][16][72]
  float* Om = (float*)smem;                // merge overlay: [128 q][68]
  float* Lm = (float*)(smem + 34816);      // merge overlay: [128] (half1's l)

  int t = threadIdx.x, w = t >> 6, lane = t & 63, ln = lane & 15, quad = lane >> 4;
  int qg = w >> 1, half = w & 1;
  int bh = blockIdx.y;
  int b = bh >> 4, h = bh & 15;
  const bf16* Q = Qg + (size_t)bh * SEQ * DH;
  const bf16* K = Kg + (size_t)bh * SEQ * DH;
  const bf16* Vt = Vtg + (size_t)bh * DH * SEQ;
  int q0 = blockIdx.x * 128 + qg * 16;

  // Q as B-operand: B[n=q(ln)][k=d(quad*8+j)] — Q already carries QSCALE
  bf16x8 bq[2];
#pragma unroll
  for (int kc = 0; kc < 2; ++kc)
    bq[kc] = *(const bf16x8*)&Q[(size_t)(q0 + ln) * DH + kc * 32 + quad * 8];

  // constant-ones B fragment for the l-accumulating MFMA
  bf16x8 ones;
#pragma unroll
  for (int j = 0; j < 8; ++j) ones[j] = (bf16)1.0f;

  floatx4 oacc[4];
  floatx4 oL = floatx4{0.f, 0.f, 0.f, 0.f};
#pragma unroll
  for (int dt = 0; dt < 4; ++dt) oacc[dt] = floatx4{0.f, 0.f, 0.f, 0.f};

  // staging roles: threads [0,512) stage half 0's tiles, [512,1024) half 1's.
  // Within a half: j<256 -> K (32B/thread), j>=256 -> V (32B/thread).
  int sh = t >> 9, st = t & 511;
  int ar = st >> 8, j = st & 255;
  int kr = j >> 2, kcol = (j & 3) * 16;  // row 0..63, 32B col chunk
  const bf16* gsrc;
  bf16* ldst;
  int gstep;
  if (ar == 0) {
    gsrc = K + (size_t)(sh * 1024 + kr) * DH + kcol;   // K row kr, d-chunk
    ldst = Ks + sh * 4608 + kr * 72 + kcol;
    gstep = 64 * DH;                                   // 64 keys per tile
  } else {
    gsrc = Vt + (size_t)kr * SEQ + sh * 1024 + kcol;   // V^T d=kr, key-chunk
    ldst = Vs + sh * 4608 + kr * 72 + kcol;
    gstep = 64;                                        // 64 keys per tile
  }

  bf16x8 p0 = *(const bf16x8*)gsrc;
  bf16x8 p1 = *(const bf16x8*)(gsrc + 8);

  const bf16* Ksh = Ks + half * 4608;
  const bf16* Vsh = Vs + half * 4608;
  bf16* Pw = Ps + w * (16 * 72);

  for (int it = 0; it < 16; ++it) {
    __syncthreads();
    *(bf16x8*)ldst = p0;
    *(bf16x8*)(ldst + 8) = p1;
    __syncthreads();

    if (it + 1 < 16) {
      const bf16* gnext = gsrc + (size_t)(it + 1) * gstep;
      p0 = *(const bf16x8*)gnext;
      p1 = *(const bf16x8*)(gnext + 8);
    }

    // S^T = K.Q^T: D[m=key][n=q]; s[nt][r] = score(q=ln, key=nt*16+quad*4+r)
    floatx4 s[4];
#pragma unroll
    for (int nt = 0; nt < 4; ++nt) s[nt] = floatx4{0.f, 0.f, 0.f, 0.f};
#pragma unroll
    for (int kc = 0; kc < 2; ++kc) {
#pragma unroll
      for (int nt = 0; nt < 4; ++nt) {
        bf16x8 ak = *(const bf16x8*)&Ksh[(nt * 16 + ln) * 72 + kc * 32 + quad * 8];
        s[nt] = __builtin_amdgcn_mfma_f32_16x16x32_bf16(ak, bq[kc], s[nt], 0, 0, 0);
      }
    }

    // p = exp2(s), raw v_exp_f32; packed b64 P writes; NO scalar li adds
#pragma unroll
    for (int nt = 0; nt < 4; ++nt) {
      float p0f = __builtin_amdgcn_exp2f(s[nt][0]);
      float p1f = __builtin_amdgcn_exp2f(s[nt][1]);
      float p2f = __builtin_amdgcn_exp2f(s[nt][2]);
      float p3f = __builtin_amdgcn_exp2f(s[nt][3]);
      bf16x4 pq = {(bf16)p0f, (bf16)p1f, (bf16)p2f, (bf16)p3f};
      *(bf16x4*)&Pw[ln * 72 + nt * 16 + quad * 4] = pq;
    }

    // O += P.V: A = P[q][key] (m=q), B = V^T[d][key] (n=d); same-wave LDS order
    // l += P.1: same A, B = ones (const reg) -> lane's oL[r] = l(quad*4+r)
#pragma unroll
    for (int kc2 = 0; kc2 < 2; ++kc2) {
      bf16x8 ap = *(const bf16x8*)&Pw[ln * 72 + kc2 * 32 + quad * 8];
      oL = __builtin_amdgcn_mfma_f32_16x16x32_bf16(ap, ones, oL, 0, 0, 0);
#pragma unroll
      for (int dt = 0; dt < 4; ++dt) {
        bf16x8 bv = *(const bf16x8*)&Vsh[(dt * 16 + ln) * 72 + kc2 * 32 + quad * 8];
        oacc[dt] = __builtin_amdgcn_mfma_f32_16x16x32_bf16(ap, bv, oacc[dt], 0, 0, 0);
      }
    }
  }

  // ---- split-K merge: O = O_half0 + O_half1, l = l0 + l1 (exact) ----
  __syncthreads();  // all compute (and last-tile LDS reads) done; reuse smem
  if (half) {
    if (ln == 0) {
#pragma unroll
      for (int r = 0; r < 4; ++r) Lm[qg * 16 + quad * 4 + r] = oL[r];
    }
#pragma unroll
    for (int r = 0; r < 4; ++r) {
      int q = qg * 16 + quad * 4 + r;
#pragma unroll
      for (int dt = 0; dt < 4; ++dt) Om[q * 68 + dt * 16 + ln] = oacc[dt][r];
    }
  }
  __syncthreads();
  if (!half) {
#pragma unroll
    for (int r = 0; r < 4; ++r) {
      int qq = qg * 16 + quad * 4 + r;
      float lt = oL[r] + Lm[qq];   // own half's l (all ln identical) + other
      float inv = 1.0f / lt;
      int ns = blockIdx.x * 128 + qq;
#pragma unroll
      for (int dt = 0; dt < 4; ++dt) {
        int d = dt * 16 + ln;
        float val = (oacc[dt][r] + Om[qq * 68 + d]) * inv;
        Og[((size_t)(b * SEQ + ns)) * EMBED + h * DH + d] = val;
      }
    }
  }
}

// ---------------------------------------------------------------------------
// ws (38 MB): q [0,4M) k [4M,8M) vt [8M,12M) wqt..wvt [12M,15M) xb [15M,19M)
// ---------------------------------------------------------------------------
extern "C" void kernel_launch(void* const* d_in, const int* in_sizes, int n_in,
                              void* d_out, int out_size, void* d_ws, size_t ws_size,
                              hipStream_t stream) {
  const int XEL = 2 * 2048 * 1024;
  const float *x, *Wq, *Wk, *Wv;
  if (in_sizes[0] == XEL) {
    x = (const float*)d_in[0];
    Wq = (const float*)d_in[1];
    Wk = (const float*)d_in[2];
    Wv = (const float*)d_in[3];
  } else {
    Wk = (const float*)d_in[0];
    Wq = (const float*)d_in[1];
    Wv = (const float*)d_in[2];
    x = (const float*)d_in[3];
  }
  bf16* ws = (bf16*)d_ws;

  const size_t M1 = 1024 * 1024;
  bf16* q_ws = ws;
  bf16* k_ws = ws + 4 * M1;
  bf16* vt_ws = ws + 8 * M1;
  bf16* wqt = ws + 12 * M1;
  bf16* wkt = ws + 13 * M1;
  bf16* wvt = ws + 14 * M1;
  bf16* xb = ws + 15 * M1;

  prep<<<dim3(256, 4), 256, 0, stream>>>(x, Wq, Wk, Wv, xb, wqt, wkt, wvt);
  qkv3<<<dim3(768), 256, 0, stream>>>(xb, wqt, wkt, wvt, q_ws, k_ws, vt_ws);
  flash<<<dim3(16, 32), 1024, 0, stream>>>(q_ws, k_ws, vt_ws, (float*)d_out);
}